// Round 2
// baseline (215.821 us; speedup 1.0000x reference)
//
#include <hip/hip_runtime.h>
#include <hip/hip_bf16.h>
#include <cstdint>
#include <cstddef>

#define B_SZ 2
#define L_SEQ 2048
#define DM 1024
#define NH 16
#define HDIM 64
#define BL (B_SZ * L_SEQ)   // 4096 rows total
#define QKV_N (3 * DM)      // 3072

typedef __attribute__((ext_vector_type(4))) float f32x4;
typedef __attribute__((ext_vector_type(8))) short bf16x8;
typedef unsigned short u16;
typedef __attribute__((ext_vector_type(4))) unsigned short u16x4;

__device__ __forceinline__ float bf2f(u16 u) {
  union { unsigned int i; float f; } c; c.i = ((unsigned int)u) << 16; return c.f;
}
__device__ __forceinline__ u16 f2bf(float f) {
  union { float f; unsigned int i; } c; c.f = f;
  unsigned int r = c.i + 0x7fffu + ((c.i >> 16) & 1u);  // RNE
  return (u16)(r >> 16);
}

__device__ __forceinline__ void gload_lds16(const void* g, void* l) {
  __builtin_amdgcn_global_load_lds(
      (const __attribute__((address_space(1))) void*)g,
      (__attribute__((address_space(3))) void*)l, 16, 0, 0);
}

// ---------------- fp32 -> bf16 convert ----------------
__global__ __launch_bounds__(256) void cvt_f32_bf16(const float* __restrict__ in,
                                                    u16* __restrict__ out, int n4) {
  int i = blockIdx.x * blockDim.x + threadIdx.x;
  const int stride = gridDim.x * blockDim.x;
  for (; i < n4; i += stride) {
    float4 v = ((const float4*)in)[i];
    u16x4 o;
    o[0] = f2bf(v.x); o[1] = f2bf(v.y); o[2] = f2bf(v.z); o[3] = f2bf(v.w);
    ((u16x4*)out)[i] = o;
  }
}

// ---------------- GEMM: C[M,N] = A[M,K] * B[N,K]^T (bf16 in, fp32 acc) ----
// 128x128 tile, BK=32, 4 waves (2x2), each wave 64x64 (4x4 frags of 16x16x32).
template <bool BF16_OUT>
__global__ __launch_bounds__(256) void gemm_bt(
    const u16* __restrict__ A, const u16* __restrict__ B,
    void* __restrict__ Cv, int M, int N, int K) {
  __shared__ u16 As[128 * 32];
  __shared__ u16 Bs[128 * 32];
  const int tid = threadIdx.x;
  const int lane = tid & 63, w = tid >> 6;
  const int lr = lane & 15, lg = lane >> 4;
  const int wr = w >> 1, wc = w & 1;
  const int bm = blockIdx.y * 128, bn = blockIdx.x * 128;

  f32x4 acc[4][4] = {};

  const int l4 = lane >> 2;                              // row within 16-row chunk
  const int csw = ((lane & 3) ^ ((lane >> 3) & 3)) * 8;  // pre-swizzled source col
  const size_t aoff0 = (size_t)(bm + (w * 2 + 0) * 16 + l4) * K + csw;
  const size_t aoff1 = (size_t)(bm + (w * 2 + 1) * 16 + l4) * K + csw;
  const size_t boff0 = (size_t)(bn + (w * 2 + 0) * 16 + l4) * K + csw;
  const size_t boff1 = (size_t)(bn + (w * 2 + 1) * 16 + l4) * K + csw;
  u16* As0 = As + (w * 2 + 0) * 512;  // wave-uniform LDS bases
  u16* As1 = As + (w * 2 + 1) * 512;
  u16* Bs0 = Bs + (w * 2 + 0) * 512;
  u16* Bs1 = Bs + (w * 2 + 1) * 512;
  const int sw_rd = (lr >> 1) & 3;

  for (int k0 = 0; k0 < K; k0 += 32) {
    gload_lds16(A + aoff0 + k0, As0);
    gload_lds16(A + aoff1 + k0, As1);
    gload_lds16(B + boff0 + k0, Bs0);
    gload_lds16(B + boff1 + k0, Bs1);
    __syncthreads();

    bf16x8 af[4], bfr[4];
#pragma unroll
    for (int mt = 0; mt < 4; ++mt) {
      const int row = wr * 64 + mt * 16 + lr;
      af[mt] = *(const bf16x8*)&As[row * 32 + ((lg ^ sw_rd) * 8)];
    }
#pragma unroll
    for (int nt = 0; nt < 4; ++nt) {
      const int row = wc * 64 + nt * 16 + lr;
      bfr[nt] = *(const bf16x8*)&Bs[row * 32 + ((lg ^ sw_rd) * 8)];
    }
#pragma unroll
    for (int mt = 0; mt < 4; ++mt)
#pragma unroll
      for (int nt = 0; nt < 4; ++nt)
        acc[mt][nt] = __builtin_amdgcn_mfma_f32_16x16x32_bf16(af[mt], bfr[nt],
                                                              acc[mt][nt], 0, 0, 0);
    __syncthreads();
  }

#pragma unroll
  for (int mt = 0; mt < 4; ++mt)
#pragma unroll
    for (int nt = 0; nt < 4; ++nt)
#pragma unroll
      for (int r = 0; r < 4; ++r) {
        const int row = bm + wr * 64 + mt * 16 + lg * 4 + r;
        const int col = bn + wc * 64 + nt * 16 + lr;
        if (BF16_OUT)
          ((u16*)Cv)[(size_t)row * N + col] = f2bf(acc[mt][nt][r]);
        else
          ((float*)Cv)[(size_t)row * N + col] = acc[mt][nt][r];
      }
}

// ---------------- fused causal flash attention (double-buffered) ----------
// grid: (L/64 q-tiles [reversed: heavy first], B*H). 256 threads = 4 waves;
// wave w owns q rows [qt*64 + w*16, +16). KVBLK=64.
// Pipeline: issue global loads for tile t+1 into regs at top of iter t,
// compute on LDS buf[t&1], write regs -> buf[(t+1)&1] at bottom, ONE barrier.
__global__ __launch_bounds__(256) void attn_fused(const u16* __restrict__ qkv,
                                                  u16* __restrict__ aout) {
  __shared__ u16 Kl[2][64 * 64];
  __shared__ u16 Vt[2][64 * 64];
  __shared__ u16 Pl[4][16 * 64];

  const int tid = threadIdx.x;
  const int lane = tid & 63, w = tid >> 6;
  const int lr = lane & 15, lg = lane >> 4;
  const int bh = blockIdx.y;
  const int b = bh >> 4, h = bh & 15;
  const int qt = (int)(gridDim.x - 1) - (int)blockIdx.x;  // heavy tiles first
  const int qbase = qt * 64;

  const u16* base = qkv + (size_t)b * L_SEQ * QKV_N;

  // staging geometry (per thread)
  const int krow = tid >> 2;            // key row this thread stages for K
  const int ks0 = (tid & 3) * 2;        // 16B slot pair within the 128B row
  const int kr7 = krow & 7;
  const int vd0 = (tid & 31) * 2;       // two d rows for V^T
  const int vkb = (tid >> 5) * 8;       // 8 keys per thread
  const int vsw = (((tid >> 5)) ^ ((vd0 >> 1) & 7)) * 8;
  const u16* gpk_base = base + (size_t)krow * QKV_N + DM + h * HDIM + ks0 * 8;
  const u16* gpv_base = base + (size_t)vkb * QKV_N + 2 * DM + h * HDIM + vd0;

  bf16x8 kr0, kr1;
  unsigned int vtmp[8];

  auto issue_loads = [&](int t) {
    const u16* gpk = gpk_base + (size_t)t * 64 * QKV_N;
    kr0 = *(const bf16x8*)(gpk);
    kr1 = *(const bf16x8*)(gpk + 8);
    const u16* gpv = gpv_base + (size_t)t * 64 * QKV_N;
#pragma unroll
    for (int j = 0; j < 8; ++j)
      vtmp[j] = *(const unsigned int*)(gpv + (size_t)j * QKV_N);
  };
  auto write_lds = [&](int buf) {
    *(bf16x8*)&Kl[buf][krow * 64 + ((ks0 ^ kr7) * 8)] = kr0;
    *(bf16x8*)&Kl[buf][krow * 64 + (((ks0 + 1) ^ kr7) * 8)] = kr1;
    bf16x8 v0, v1;
#pragma unroll
    for (int j = 0; j < 8; ++j) {
      v0[j] = (short)(vtmp[j] & 0xffffu);
      v1[j] = (short)(vtmp[j] >> 16);
    }
    *(bf16x8*)&Vt[buf][vd0 * 64 + vsw] = v0;
    *(bf16x8*)&Vt[buf][(vd0 + 1) * 64 + vsw] = v1;
  };

  // Q fragments (A-operand layout), pre-scaled by 1/sqrt(64)=0.125
  bf16x8 aq[2];
  {
    const int qrow = qbase + w * 16 + lr;
    const u16* qp = base + (size_t)qrow * QKV_N + h * HDIM + lg * 8;
#pragma unroll
    for (int ds = 0; ds < 2; ++ds) {
      bf16x8 t = *(const bf16x8*)(qp + ds * 32);
#pragma unroll
      for (int i = 0; i < 8; ++i)
        t[i] = (short)f2bf(bf2f((u16)t[i]) * 0.125f);
      aq[ds] = t;
    }
  }

  float mrow[4], lrow[4];
  f32x4 o[4] = {};
#pragma unroll
  for (int r = 0; r < 4; ++r) { mrow[r] = -1e30f; lrow[r] = 0.f; }

  const int qout = qbase + w * 16 + lg * 4;  // +r = this lane's output rows

  // prologue: stage tile 0
  issue_loads(0);
  write_lds(0);
  __syncthreads();

  for (int t = 0; t <= qt; ++t) {
    const int cur = t & 1;
    if (t < qt) issue_loads(t + 1);  // overlap HBM latency with compute

    // ---- S = (Q/8)·K^T : D-layout row q = lg*4+r, col k = lr (+16*kt)
    f32x4 s[4] = {};
#pragma unroll
    for (int ds = 0; ds < 2; ++ds)
#pragma unroll
      for (int kt = 0; kt < 4; ++kt) {
        const int kro = kt * 16 + lr;
        const bf16x8 bk =
            *(const bf16x8*)&Kl[cur][kro * 64 + (((ds * 4 + lg) ^ (kro & 7)) * 8)];
        s[kt] = __builtin_amdgcn_mfma_f32_16x16x32_bf16(aq[ds], bk, s[kt], 0, 0, 0);
      }

    // ---- causal mask: only the diagonal tile needs it (wave-uniform branch)
    if (t == qt) {
      const int kb = t * 64 + lr;
#pragma unroll
      for (int kt = 0; kt < 4; ++kt) {
        const int k = kb + kt * 16;
#pragma unroll
        for (int r = 0; r < 4; ++r)
          if (k > qout + r) s[kt][r] = -1e30f;
      }
    }

    // ---- online softmax (16-lane group shuffles)
    float tmx[4];
#pragma unroll
    for (int r = 0; r < 4; ++r)
      tmx[r] = fmaxf(fmaxf(s[0][r], s[1][r]), fmaxf(s[2][r], s[3][r]));
#pragma unroll
    for (int off = 1; off < 16; off <<= 1)
#pragma unroll
      for (int r = 0; r < 4; ++r)
        tmx[r] = fmaxf(tmx[r], __shfl_xor(tmx[r], off));

    float alpha[4], rs[4];
#pragma unroll
    for (int r = 0; r < 4; ++r) {
      const float mnew = fmaxf(mrow[r], tmx[r]);
      alpha[r] = exp2f((mrow[r] - mnew) * 1.44269504f);
      mrow[r] = mnew;
      rs[r] = 0.f;
    }
#pragma unroll
    for (int kt = 0; kt < 4; ++kt)
#pragma unroll
      for (int r = 0; r < 4; ++r) {
        const float p = exp2f((s[kt][r] - mrow[r]) * 1.44269504f);
        s[kt][r] = p;
        rs[r] += p;
      }
#pragma unroll
    for (int off = 1; off < 16; off <<= 1)
#pragma unroll
      for (int r = 0; r < 4; ++r)
        rs[r] += __shfl_xor(rs[r], off);
#pragma unroll
    for (int r = 0; r < 4; ++r) lrow[r] = lrow[r] * alpha[r] + rs[r];
#pragma unroll
    for (int dt = 0; dt < 4; ++dt)
#pragma unroll
      for (int r = 0; r < 4; ++r) o[dt][r] *= alpha[r];

    // ---- P: D-layout -> A-layout via per-wave swizzled LDS (no barrier)
#pragma unroll
    for (int kt = 0; kt < 4; ++kt) {
      const int k = kt * 16 + lr;
#pragma unroll
      for (int r = 0; r < 4; ++r) {
        const int q = lg * 4 + r;
        Pl[w][q * 64 + (((k >> 3) ^ (q & 7)) * 8) + (k & 7)] = f2bf(s[kt][r]);
      }
    }
    // ---- PV: O[q][d] += P[q][k] * V[k][d]
#pragma unroll
    for (int ks = 0; ks < 2; ++ks) {
      const bf16x8 ap =
          *(const bf16x8*)&Pl[w][lr * 64 + (((ks * 4 + lg) ^ (lr & 7)) * 8)];
#pragma unroll
      for (int dt = 0; dt < 4; ++dt) {
        const int drow = dt * 16 + lr;
        const bf16x8 bv = *(const bf16x8*)
            &Vt[cur][drow * 64 + (((ks * 4 + lg) ^ ((drow >> 1) & 7)) * 8)];
        o[dt] = __builtin_amdgcn_mfma_f32_16x16x32_bf16(ap, bv, o[dt], 0, 0, 0);
      }
    }

    // ---- write next tile into the other buffer; single barrier per iter
    if (t < qt) write_lds(cur ^ 1);
    __syncthreads();
  }

  // ---- epilogue: O / l -> aout[b, q, h*64 + d] (bf16)
  float inv[4];
#pragma unroll
  for (int r = 0; r < 4; ++r) inv[r] = 1.f / lrow[r];
#pragma unroll
  for (int dt = 0; dt < 4; ++dt)
#pragma unroll
    for (int r = 0; r < 4; ++r) {
      const int q = qout + r;
      aout[(size_t)(b * L_SEQ + q) * DM + h * HDIM + dt * 16 + lr] =
          f2bf(o[dt][r] * inv[r]);
    }
}

// ---------------- host launch ----------------
extern "C" void kernel_launch(void* const* d_in, const int* in_sizes, int n_in,
                              void* d_out, int out_size, void* d_ws, size_t ws_size,
                              hipStream_t stream) {
  (void)in_sizes; (void)n_in; (void)out_size; (void)ws_size;
  const float* x = (const float*)d_in[0];     // [4096][1024]
  const float* wqkv = (const float*)d_in[1];  // [3072][1024]
  const float* wo = (const float*)d_in[2];    // [1024][1024]

  char* ws = (char*)d_ws;
  // layout (40 MB): x_bf 8MB | w_bf 6MB | wo_bf 2MB | qkv_bf 24MB
  // x_bf region is reused as attention output (x no longer needed then).
  u16* x_bf = (u16*)(ws);
  u16* w_bf = (u16*)(ws + (size_t)(8u << 20));
  u16* wo_bf = (u16*)(ws + (size_t)(14u << 20));
  u16* qkv_bf = (u16*)(ws + (size_t)(16u << 20));
  u16* ao_bf = x_bf;  // alias

  cvt_f32_bf16<<<2048, 256, 0, stream>>>(x, x_bf, BL * DM / 4);
  cvt_f32_bf16<<<2048, 256, 0, stream>>>(wqkv, w_bf, QKV_N * DM / 4);
  cvt_f32_bf16<<<1024, 256, 0, stream>>>(wo, wo_bf, DM * DM / 4);

  dim3 g1(QKV_N / 128, BL / 128);  // (24, 32)
  gemm_bt<true><<<g1, 256, 0, stream>>>(x_bf, w_bf, (void*)qkv_bf, BL, QKV_N, DM);

  dim3 g2(L_SEQ / 64, B_SZ * NH);  // (32, 32)
  attn_fused<<<g2, 256, 0, stream>>>(qkv_bf, ao_bf);

  dim3 g3(DM / 128, BL / 128);  // (8, 32)
  gemm_bt<false><<<g3, 256, 0, stream>>>(ao_bf, wo_bf, d_out, BL, DM, DM);
}

// Round 3
// 139.304 us; speedup vs baseline: 1.5493x; 1.5493x over previous
//
#include <hip/hip_runtime.h>
#include <hip/hip_bf16.h>
#include <cstdint>
#include <cstddef>

#define B_SZ 2
#define L_SEQ 2048
#define DM 1024
#define NH 16
#define HDIM 64
#define BL (B_SZ * L_SEQ)   // 4096 rows total
#define QKV_N (3 * DM)      // 3072

typedef __attribute__((ext_vector_type(4))) float f32x4;
typedef __attribute__((ext_vector_type(16))) float f32x16;
typedef __attribute__((ext_vector_type(8))) short bf16x8;
typedef __attribute__((ext_vector_type(4))) unsigned int u32x4;
typedef unsigned short u16;
typedef __attribute__((ext_vector_type(4))) unsigned short u16x4;

__device__ __forceinline__ float bf2f(u16 u) {
  union { unsigned int i; float f; } c; c.i = ((unsigned int)u) << 16; return c.f;
}
__device__ __forceinline__ u16 f2bf(float f) {
  union { float f; unsigned int i; } c; c.f = f;
  unsigned int r = c.i + 0x7fffu + ((c.i >> 16) & 1u);  // RNE
  return (u16)(r >> 16);
}

__device__ __forceinline__ void gload_lds16(const void* g, void* l) {
  __builtin_amdgcn_global_load_lds(
      (const __attribute__((address_space(1))) void*)g,
      (__attribute__((address_space(3))) void*)l, 16, 0, 0);
}

__device__ __forceinline__ f32x16 mfma32(bf16x8 a, bf16x8 b, f32x16 c) {
  return __builtin_amdgcn_mfma_f32_32x32x16_bf16(a, b, c, 0, 0, 0);
}

// packed f32 pair -> one u32 of 2 bf16 (lo in [15:0])
__device__ __forceinline__ unsigned cvtpk(float lo, float hi) {
  unsigned r;
  asm("v_cvt_pk_bf16_f32 %0, %1, %2" : "=v"(r) : "v"(lo), "v"(hi));
  return r;
}
// swap upper 32 lanes of a with lower 32 lanes of b (both updated)
__device__ __forceinline__ void plswap(unsigned& a, unsigned& b) {
  asm("v_permlane32_swap_b32 %0, %1" : "+v"(a), "+v"(b));
}

// Take 8 regs of a 32x32 D-layout group (rows (r&3)+8*(r>>2)+4*hi), BASE=0 or 8
// (i.e. one 16-row chunk), convert to bf16 and redistribute into the B-fragment
// layout for mfma32 (lane holds rows hi*8..hi*8+7 of the chunk, packed).
template <int BASE>
__device__ __forceinline__ bf16x8 pack_bfrag(const f32x16& v) {
  unsigned a  = cvtpk(v[BASE + 0], v[BASE + 1]);
  unsigned a2 = cvtpk(v[BASE + 2], v[BASE + 3]);
  unsigned b  = cvtpk(v[BASE + 4], v[BASE + 5]);
  unsigned b2 = cvtpk(v[BASE + 6], v[BASE + 7]);
  plswap(a, b);    // a -> frag word0, b -> frag word2
  plswap(a2, b2);  // a2 -> frag word1, b2 -> frag word3
  u32x4 fw; fw[0] = a; fw[1] = a2; fw[2] = b; fw[3] = b2;
  return __builtin_bit_cast(bf16x8, fw);
}

// ---------------- fp32 -> bf16 convert ----------------
__global__ __launch_bounds__(256) void cvt_f32_bf16(const float* __restrict__ in,
                                                    u16* __restrict__ out, int n4) {
  int i = blockIdx.x * blockDim.x + threadIdx.x;
  const int stride = gridDim.x * blockDim.x;
  for (; i < n4; i += stride) {
    float4 v = ((const float4*)in)[i];
    u16x4 o;
    o[0] = f2bf(v.x); o[1] = f2bf(v.y); o[2] = f2bf(v.z); o[3] = f2bf(v.w);
    ((u16x4*)out)[i] = o;
  }
}

// ---------------- GEMM: C[M,N] = A[M,K] * B[N,K]^T (bf16 in, fp32 acc) ----
template <bool BF16_OUT>
__global__ __launch_bounds__(256) void gemm_bt(
    const u16* __restrict__ A, const u16* __restrict__ B,
    void* __restrict__ Cv, int M, int N, int K) {
  __shared__ u16 As[128 * 32];
  __shared__ u16 Bs[128 * 32];
  const int tid = threadIdx.x;
  const int lane = tid & 63, w = tid >> 6;
  const int lr = lane & 15, lg = lane >> 4;
  const int wr = w >> 1, wc = w & 1;
  const int bm = blockIdx.y * 128, bn = blockIdx.x * 128;

  f32x4 acc[4][4] = {};

  const int l4 = lane >> 2;
  const int csw = ((lane & 3) ^ ((lane >> 3) & 3)) * 8;
  const size_t aoff0 = (size_t)(bm + (w * 2 + 0) * 16 + l4) * K + csw;
  const size_t aoff1 = (size_t)(bm + (w * 2 + 1) * 16 + l4) * K + csw;
  const size_t boff0 = (size_t)(bn + (w * 2 + 0) * 16 + l4) * K + csw;
  const size_t boff1 = (size_t)(bn + (w * 2 + 1) * 16 + l4) * K + csw;
  u16* As0 = As + (w * 2 + 0) * 512;
  u16* As1 = As + (w * 2 + 1) * 512;
  u16* Bs0 = Bs + (w * 2 + 0) * 512;
  u16* Bs1 = Bs + (w * 2 + 1) * 512;
  const int sw_rd = (lr >> 1) & 3;

  for (int k0 = 0; k0 < K; k0 += 32) {
    gload_lds16(A + aoff0 + k0, As0);
    gload_lds16(A + aoff1 + k0, As1);
    gload_lds16(B + boff0 + k0, Bs0);
    gload_lds16(B + boff1 + k0, Bs1);
    __syncthreads();

    bf16x8 af[4], bfr[4];
#pragma unroll
    for (int mt = 0; mt < 4; ++mt) {
      const int row = wr * 64 + mt * 16 + lr;
      af[mt] = *(const bf16x8*)&As[row * 32 + ((lg ^ sw_rd) * 8)];
    }
#pragma unroll
    for (int nt = 0; nt < 4; ++nt) {
      const int row = wc * 64 + nt * 16 + lr;
      bfr[nt] = *(const bf16x8*)&Bs[row * 32 + ((lg ^ sw_rd) * 8)];
    }
#pragma unroll
    for (int mt = 0; mt < 4; ++mt)
#pragma unroll
      for (int nt = 0; nt < 4; ++nt)
        acc[mt][nt] = __builtin_amdgcn_mfma_f32_16x16x32_bf16(af[mt], bfr[nt],
                                                              acc[mt][nt], 0, 0, 0);
    __syncthreads();
  }

#pragma unroll
  for (int mt = 0; mt < 4; ++mt)
#pragma unroll
    for (int nt = 0; nt < 4; ++nt)
#pragma unroll
      for (int r = 0; r < 4; ++r) {
        const int row = bm + wr * 64 + mt * 16 + lg * 4 + r;
        const int col = bn + wc * 64 + nt * 16 + lr;
        if (BF16_OUT)
          ((u16*)Cv)[(size_t)row * N + col] = f2bf(acc[mt][nt][r]);
        else
          ((float*)Cv)[(size_t)row * N + col] = acc[mt][nt][r];
      }
}

// ---------------- fused causal flash attention, 32x32 swapped-operand ------
// 512 blocks: id -> (slot = id>>5, bh = id&31); qt = slot<8 ? 15-2*slot : 2*(slot-8)
// (complementary weights so co-resident blocks sum to ~constant work).
// Block: 4 waves, wave w owns q rows [qt*128 + w*32, +32). KVBLK=64.
// S^T = mfma32(K, Q): lane q = lane&31 holds keys (r&3)+8*(r>>2)+4*hi (+32g).
// Softmax fully in-register; P -> B-frags via cvt_pk + permlane32_swap.
// O^T = mfma32(V^T, P^T), accumulated over tiles; epilogue packs d-contiguous.
__global__ __launch_bounds__(256) void attn_fused(const u16* __restrict__ qkv,
                                                  u16* __restrict__ aout) {
  __shared__ u16 Kl[2][64 * 64];
  __shared__ u16 Vt[2][64 * 64];

  const int tid = threadIdx.x;
  const int lane = tid & 63, w = tid >> 6;
  const int l31 = lane & 31, hi = lane >> 5;
  const int id = (int)blockIdx.x;
  const int bh = id & 31, slot = id >> 5;
  const int qt = slot < 8 ? 15 - 2 * slot : 2 * (slot - 8);
  const int b = bh >> 4, h = bh & 15;
  const u16* base = qkv + (size_t)b * L_SEQ * QKV_N;
  const int W = qt * 128 + w * 32;     // wave's first q row
  const int nt = 2 * qt + 2;           // kv tiles for this q-tile
  const int qrow = W + l31;            // this lane's q row

  // ---- staging geometry (256 threads)
  const int krow = tid >> 2;           // K: key row, 2 slots per thread
  const int ks0 = (tid & 3) * 2;
  const int kr7 = krow & 7;
  const int vd0 = (tid & 31) * 2;      // V^T: two d rows per thread
  const int vkb = tid >> 5;            // slot index (8 keys)
  const u16* gpk_base = base + (size_t)krow * QKV_N + DM + h * HDIM + ks0 * 8;
  const u16* gpv_base = base + (size_t)(vkb * 8) * QKV_N + 2 * DM + h * HDIM + vd0;

  bf16x8 kr0, kr1;
  unsigned int vtmp[8];

  auto issue_loads = [&](int t) {
    const u16* gpk = gpk_base + (size_t)t * 64 * QKV_N;
    kr0 = *(const bf16x8*)(gpk);
    kr1 = *(const bf16x8*)(gpk + 8);
    const u16* gpv = gpv_base + (size_t)t * 64 * QKV_N;
#pragma unroll
    for (int j = 0; j < 8; ++j)
      vtmp[j] = *(const unsigned int*)(gpv + (size_t)j * QKV_N);
  };
  auto write_lds = [&](int buf) {
    *(bf16x8*)&Kl[buf][krow * 64 + ((ks0 ^ kr7) * 8)] = kr0;
    *(bf16x8*)&Kl[buf][krow * 64 + (((ks0 + 1) ^ kr7) * 8)] = kr1;
    bf16x8 v0, v1;
#pragma unroll
    for (int j = 0; j < 8; ++j) {
      v0[j] = (short)(vtmp[j] & 0xffffu);
      v1[j] = (short)(vtmp[j] >> 16);
    }
    *(bf16x8*)&Vt[buf][vd0 * 64 + ((vkb ^ (vd0 & 7)) * 8)] = v0;
    *(bf16x8*)&Vt[buf][(vd0 + 1) * 64 + ((vkb ^ ((vd0 + 1) & 7)) * 8)] = v1;
  };

  // ---- Q B-frags: lane holds Q[qrow][dc*16 + hi*8 .. +7], scaled by
  // 0.125 (1/sqrt(64)) * log2(e) so softmax uses exp2 directly.
  bf16x8 bq[4];
  {
    const u16* qp = base + (size_t)qrow * QKV_N + h * HDIM + hi * 8;
#pragma unroll
    for (int dc = 0; dc < 4; ++dc) {
      bf16x8 tq = *(const bf16x8*)(qp + dc * 16);
#pragma unroll
      for (int i = 0; i < 8; ++i)
        tq[i] = (short)f2bf(bf2f((u16)tq[i]) * 0.18033688f);
      bq[dc] = tq;
    }
  }

  f32x16 acc0 = {}, acc1 = {};  // O^T: d rows [0,32) and [32,64), col q
  float mrow = -1e30f, lrow = 0.f;

  issue_loads(0);
  write_lds(0);
  __syncthreads();

  for (int t = 0; t < nt; ++t) {
    const int cur = t & 1;
    if (t + 1 < nt) issue_loads(t + 1);

    if (64 * t <= W + 31) {  // wave-uniform: this wave still needs keys
      // ---- S^T = K * Q^T over 2 key groups x 4 d-chunks
      f32x16 s0 = {}, s1 = {};
      const int lsw = lane & 7;
#pragma unroll
      for (int dc = 0; dc < 4; ++dc) {
        const int sl = ((dc * 2 + hi) ^ lsw) * 8;
        const bf16x8 k0 = *(const bf16x8*)&Kl[cur][l31 * 64 + sl];
        const bf16x8 k1 = *(const bf16x8*)&Kl[cur][(32 + l31) * 64 + sl];
        s0 = mfma32(k0, bq[dc], s0);
        s1 = mfma32(k1, bq[dc], s1);
      }

      // ---- causal mask (only the wave's diagonal-band tile)
      if (64 * t + 63 > W) {
#pragma unroll
        for (int r = 0; r < 16; ++r) {
          const int kg = t * 64 + (r & 3) + 8 * (r >> 2) + 4 * hi;
          if (kg > qrow) s0[r] = -1e30f;
          if (kg + 32 > qrow) s1[r] = -1e30f;
        }
      }

      // ---- tile max (in-lane over 32, then cross-half)
      float px = fmaxf(s0[0], s1[0]);
#pragma unroll
      for (int r = 1; r < 16; ++r) px = fmaxf(px, fmaxf(s0[r], s1[r]));
      px = fmaxf(px, __shfl_xor(px, 32));

      // ---- defer-max rescale (T13)
      if (!__all(px <= mrow + 8.f)) {
        const float mnew = fmaxf(mrow, px);
        const float alpha = exp2f(mrow - mnew);
        mrow = mnew;
        lrow *= alpha;
#pragma unroll
        for (int i = 0; i < 16; ++i) { acc0[i] *= alpha; acc1[i] *= alpha; }
      }

      // ---- P = exp2(S - m), row sum
      float rs = 0.f;
#pragma unroll
      for (int r = 0; r < 16; ++r) {
        s0[r] = exp2f(s0[r] - mrow); rs += s0[r];
        s1[r] = exp2f(s1[r] - mrow); rs += s1[r];
      }
      rs += __shfl_xor(rs, 32);
      lrow += rs;

      // ---- P -> bf16 B-frags (4 chunks of 16 keys), in-register
      const bf16x8 pf0 = pack_bfrag<0>(s0);
      const bf16x8 pf1 = pack_bfrag<8>(s0);
      const bf16x8 pf2 = pack_bfrag<0>(s1);
      const bf16x8 pf3 = pack_bfrag<8>(s1);

      // ---- O^T += V^T * P^T
#pragma unroll
      for (int c = 0; c < 4; ++c) {
        const bf16x8 pf = c == 0 ? pf0 : c == 1 ? pf1 : c == 2 ? pf2 : pf3;
        const int sl = ((c * 2 + hi) ^ lsw) * 8;
        const bf16x8 va = *(const bf16x8*)&Vt[cur][l31 * 64 + sl];
        const bf16x8 vb = *(const bf16x8*)&Vt[cur][(32 + l31) * 64 + sl];
        acc0 = mfma32(va, pf, acc0);
        acc1 = mfma32(vb, pf, acc1);
      }
    }

    if (t + 1 < nt) write_lds((t + 1) & 1);
    __syncthreads();
  }

  // ---- epilogue: O = O^T / l, repack to d-contiguous frags, 16B stores
  const float inv = 1.f / lrow;
#pragma unroll
  for (int i = 0; i < 16; ++i) { acc0[i] *= inv; acc1[i] *= inv; }
  const bf16x8 of0 = pack_bfrag<0>(acc0);  // d = 0*16 + hi*8 + j
  const bf16x8 of1 = pack_bfrag<8>(acc0);  // d = 16 + hi*8 + j
  const bf16x8 of2 = pack_bfrag<0>(acc1);  // d = 32 + hi*8 + j
  const bf16x8 of3 = pack_bfrag<8>(acc1);  // d = 48 + hi*8 + j
  u16* op = aout + (size_t)(b * L_SEQ + qrow) * DM + h * HDIM + hi * 8;
  *(bf16x8*)(op + 0)  = of0;
  *(bf16x8*)(op + 16) = of1;
  *(bf16x8*)(op + 32) = of2;
  *(bf16x8*)(op + 48) = of3;
}

// ---------------- host launch ----------------
extern "C" void kernel_launch(void* const* d_in, const int* in_sizes, int n_in,
                              void* d_out, int out_size, void* d_ws, size_t ws_size,
                              hipStream_t stream) {
  (void)in_sizes; (void)n_in; (void)out_size; (void)ws_size;
  const float* x = (const float*)d_in[0];     // [4096][1024]
  const float* wqkv = (const float*)d_in[1];  // [3072][1024]
  const float* wo = (const float*)d_in[2];    // [1024][1024]

  char* ws = (char*)d_ws;
  u16* x_bf = (u16*)(ws);
  u16* w_bf = (u16*)(ws + (size_t)(8u << 20));
  u16* wo_bf = (u16*)(ws + (size_t)(14u << 20));
  u16* qkv_bf = (u16*)(ws + (size_t)(16u << 20));
  u16* ao_bf = x_bf;  // alias (x consumed by then)

  cvt_f32_bf16<<<2048, 256, 0, stream>>>(x, x_bf, BL * DM / 4);
  cvt_f32_bf16<<<2048, 256, 0, stream>>>(wqkv, w_bf, QKV_N * DM / 4);
  cvt_f32_bf16<<<1024, 256, 0, stream>>>(wo, wo_bf, DM * DM / 4);

  dim3 g1(QKV_N / 128, BL / 128);  // (24, 32)
  gemm_bt<true><<<g1, 256, 0, stream>>>(x_bf, w_bf, (void*)qkv_bf, BL, QKV_N, DM);

  attn_fused<<<dim3(512), 256, 0, stream>>>(qkv_bf, ao_bf);

  dim3 g3(DM / 128, BL / 128);  // (8, 32)
  gemm_bt<false><<<g3, 256, 0, stream>>>(ao_bf, wo_bf, d_out, BL, DM, DM);
}